// Round 7
// baseline (554.192 us; speedup 1.0000x reference)
//
#include <hip/hip_runtime.h>
#include <cfloat>

typedef unsigned long long ull;
typedef int v2i __attribute__((ext_vector_type(2)));

constexpr int BDIM = 256;
constexpr int NPTS = 8192;
constexpr int QPTS = 2048;     // points per quarter-block
constexpr int KSEL = 16;
constexpr int PD_  = 16;
constexpr int DIN  = 20;
constexpr int HID  = 128;
constexpr int DOUT = 256;
constexpr int CAP  = 256;      // candidate capacity (E[cnt] ~ 40)

__device__ __forceinline__ ull mkkey(float d, int n) {
    // positive-float bits are order-monotone; low 32 bits = index (tie-break)
    return ((ull)__float_as_uint(d) << 32) | (unsigned int)n;
}

// ---------- f32 wave butterfly min (DPP + 1 ds_swizzle + permlane32) --------
template<int CTRL>
__device__ __forceinline__ float dppmin_f32(float v) {
    const int o = __builtin_amdgcn_mov_dpp(__float_as_int(v), CTRL, 0xF, 0xF, true);
    return fminf(v, __int_as_float(o));
}
__device__ __forceinline__ float swz16min_f32(float v) {
    const int o = __builtin_amdgcn_ds_swizzle(__float_as_int(v), 0x401F); // xor16
    return fminf(v, __int_as_float(o));
}
__device__ __forceinline__ float half32min_f32(float v, int lane) {
#if __has_builtin(__builtin_amdgcn_permlane32_swap)
    v2i r = __builtin_amdgcn_permlane32_swap(__float_as_int(v), __float_as_int(v), false, false);
    const int o = (lane < 32) ? r[1] : r[0];
#else
    const int o = __shfl_xor(__float_as_int(v), 32, 64);
#endif
    return fminf(v, __int_as_float(o));
}
__device__ __forceinline__ float wavemin_f32(float v, int lane) {
    v = dppmin_f32<0xB1>(v);    // quad_perm xor1
    v = dppmin_f32<0x4E>(v);    // quad_perm xor2
    v = dppmin_f32<0x124>(v);   // row_ror:4
    v = dppmin_f32<0x128>(v);   // row_ror:8
    v = swz16min_f32(v);        // xor16
    v = half32min_f32(v, lane); // cross-32
    return v;
}

// ---- fused: per-quarter select; last quarter of a row runs the row's MLP ---
__global__ __launch_bounds__(BDIM, 8) void fused_kernel(
    const float* __restrict__ lg,      // (2,)
    const float* __restrict__ coords,  // (B, N, 3)
    const float* __restrict__ params,  // (B, N, 16)
    const float* __restrict__ W1, const float* __restrict__ b1,
    const float* __restrict__ W2, const float* __restrict__ b2,
    const float* __restrict__ W3, const float* __restrict__ b3,
    float* __restrict__ out,           // (B, 256)
    ull* __restrict__ keys,            // (B, 4, 16) ws
    int* __restrict__ cnt)             // (B,) ws, zeroed per launch
{
    __shared__ float twave[4];
    __shared__ ull   cand[CAP];
    __shared__ int   ccnt;
    __shared__ int   isLast;
    // finisher-phase LDS
    __shared__ ull   wkeys[64];
    __shared__ int   selb[KSEL];
    __shared__ float pbuf[KSEL][PD_];
    __shared__ float cbuf[KSEL][2];
    __shared__ float xvec[DIN];
    __shared__ float h1s[HID];
    __shared__ float h2s[HID];

    const int blk  = blockIdx.x;
    const int row  = blk >> 2;
    const int q    = blk & 3;
    const int tid  = threadIdx.x;
    const int lane = tid & 63;
    const int wid  = tid >> 6;
    const float lg0 = lg[0];
    const float lg1 = lg[1];

    if (tid == 0) ccnt = 0;

    // ---- distances: 8 points/thread (2 float4-triples) ----
    const float4* c4 = reinterpret_cast<const float4*>(coords)
                       + (size_t)row * (NPTS * 3 / 4) + q * (QPTS * 3 / 4);
    float dd[8];
    #pragma unroll
    for (int it = 0; it < 2; ++it) {
        const int g = it * BDIM + tid;
        const float4 qa = c4[3 * g + 0];
        const float4 qb = c4[3 * g + 1];
        const float4 qc = c4[3 * g + 2];
        const float px[4] = {qa.x, qa.w, qb.z, qc.y};
        const float py[4] = {qa.y, qb.x, qb.w, qc.z};
        #pragma unroll
        for (int j = 0; j < 4; ++j) {
            // match numpy rounding: sub, sub, mul, mul, add — no fma contraction
            const float t0 = __fsub_rn(lg0, px[j]);
            const float t1 = __fsub_rn(lg1, py[j]);
            dd[it * 4 + j] = __fadd_rn(__fmul_rn(t0, t0), __fmul_rn(t1, t1));
        }
    }

    // ---- thread min ----
    const float m = fminf(fminf(fminf(dd[0], dd[1]), fminf(dd[2], dd[3])),
                          fminf(fminf(dd[4], dd[5]), fminf(dd[6], dd[7])));

    // ---- per-wave 4th-smallest thread-min; T = max over waves ----
    // (each wave then has >=4 thread-mins <= T -> >=16 points <= T block-wide)
    float tw;
    {
        float loc = m;
        #pragma unroll
        for (int r = 0; r < 4; ++r) {
            const float wmin = wavemin_f32(loc, lane);
            if (r == 3) { tw = wmin; break; }
            if (loc == wmin) loc = FLT_MAX;
        }
    }
    if (lane == 0) twave[wid] = tw;
    __syncthreads();
    const float T = fmaxf(fmaxf(twave[0], twave[1]), fmaxf(twave[2], twave[3]));

    // ---- candidates with d <= T (contains all quarter-top-16) ----
    #pragma unroll
    for (int it = 0; it < 2; ++it) {
        #pragma unroll
        for (int j = 0; j < 4; ++j) {
            const float d = dd[it * 4 + j];
            if (d <= T) {
                const int pos = atomicAdd(&ccnt, 1);
                if (pos < CAP)
                    cand[pos] = mkkey(d, (q << 11) + (it << 10) + (tid << 2) + j);
            }
        }
    }
    __syncthreads();

    // ---- exact quarter-top-16 by rank (unique keys -> rank is exact) ----
    if (wid == 0) {
        int cc = ccnt; if (cc > CAP) cc = CAP;
        for (int s = lane; s < cc; s += 64) {
            const ull k = cand[s];
            int rank = 0;
            for (int j = 0; j < cc; ++j) rank += (cand[j] < k);
            if (rank < KSEL) keys[(size_t)row * 64 + q * 16 + rank] = k;
        }
    }
    __syncthreads();

    // ---- completion protocol: last quarter of the row becomes finisher ----
    __threadfence();                       // release our key writes
    if (tid == 0) isLast = (atomicAdd(&cnt[row], 1) == 3);
    __syncthreads();
    if (!isLast) return;
    __threadfence();                       // acquire other quarters' keys

    // ================= finisher: merge + gather + feature + MLP ============
    if (tid < 64) wkeys[tid] = keys[(size_t)row * 64 + tid];
    __syncthreads();
    if (tid < 64) {
        const ull myk = wkeys[tid];
        int rank = 0;
        #pragma unroll 8
        for (int j = 0; j < 64; ++j) rank += (wkeys[j] < myk);
        if (rank < KSEL) selb[rank] = (int)(unsigned)myk;   // argsort order
    }
    __syncthreads();

    {   // params gather: 256 threads = 16 neighbors x 16 dims
        const int k = tid >> 4, p = tid & 15;
        pbuf[k][p] = params[((size_t)row * NPTS + selb[k]) * PD_ + p];
    }
    if (tid < 2 * KSEL) {
        const int k = tid >> 1, c = tid & 1;
        cbuf[k][c] = coords[((size_t)row * NPTS + selb[k]) * 3 + c];
    }
    __syncthreads();

    if (tid < DIN) {
        float v;
        if (tid < 2) {
            v = lg[tid];
        } else if (tid < 4) {
            float s = 0.f;
            for (int k = 0; k < KSEL; ++k) s += cbuf[k][tid - 2];
            v = s * (1.f / 16.f);
        } else {
            float s = 0.f;
            for (int k = 0; k < KSEL; ++k) s += pbuf[k][tid - 4];
            v = s * (1.f / 16.f);
        }
        xvec[tid] = v;
    }
    __syncthreads();

    if (tid < HID) {
        float acc = b1[tid];
        #pragma unroll
        for (int i = 0; i < DIN; ++i) acc = fmaf(xvec[i], W1[i * HID + tid], acc);
        h1s[tid] = fmaxf(acc, 0.f);
    }
    __syncthreads();
    if (tid < HID) {
        float acc = b2[tid];
        #pragma unroll 16
        for (int i = 0; i < HID; ++i) acc = fmaf(h1s[i], W2[i * HID + tid], acc);
        h2s[tid] = fmaxf(acc, 0.f);
    }
    __syncthreads();
    {
        float acc = b3[tid];
        #pragma unroll 16
        for (int i = 0; i < HID; ++i) acc = fmaf(h2s[i], W3[i * DOUT + tid], acc);
        out[(size_t)row * DOUT + tid] = acc;
    }
}

extern "C" void kernel_launch(void* const* d_in, const int* in_sizes, int n_in,
                              void* d_out, int out_size, void* d_ws, size_t ws_size,
                              hipStream_t stream) {
    const float* lg     = (const float*)d_in[0];
    const float* coords = (const float*)d_in[1];
    const float* params = (const float*)d_in[2];
    const float* W1     = (const float*)d_in[3];
    const float* b1     = (const float*)d_in[4];
    const float* W2     = (const float*)d_in[5];
    const float* b2     = (const float*)d_in[6];
    const float* W3     = (const float*)d_in[7];
    const float* b3     = (const float*)d_in[8];
    float* out          = (float*)d_out;

    const int Brows = in_sizes[1] / (NPTS * 3);  // 1024
    const size_t keybytes = (size_t)Brows * 64 * sizeof(ull);   // 512 KB
    ull* keys = (ull*)d_ws;
    int* cnt  = (int*)((char*)d_ws + keybytes);

    // counters must start at 0 each launch (ws is poisoned, not re-zeroed)
    hipMemsetAsync(cnt, 0, (size_t)Brows * sizeof(int), stream);
    fused_kernel<<<dim3(Brows * 4), dim3(BDIM), 0, stream>>>(
        lg, coords, params, W1, b1, W2, b2, W3, b3, out, keys, cnt);
}

// Round 8
// 33.668 us; speedup vs baseline: 16.4605x; 16.4605x over previous
//
#include <hip/hip_runtime.h>
#include <cfloat>

typedef unsigned long long ull;
typedef int v2i __attribute__((ext_vector_type(2)));

constexpr int BDIM = 256;
constexpr int NPTS = 8192;
constexpr int QPTS = 2048;     // points per quarter-block
constexpr int KSEL = 16;
constexpr int PD_  = 16;
constexpr int DIN  = 20;
constexpr int HID  = 128;
constexpr int DOUT = 256;
constexpr int CAP  = 256;      // candidate capacity (E[cnt] ~ 40)

__device__ __forceinline__ ull mkkey(float d, int n) {
    // positive-float bits are order-monotone; low 32 bits = index (tie-break)
    return ((ull)__float_as_uint(d) << 32) | (unsigned int)n;
}

// ---------- f32 wave butterfly min (DPP + 1 ds_swizzle + permlane32) --------
template<int CTRL>
__device__ __forceinline__ float dppmin_f32(float v) {
    const int o = __builtin_amdgcn_mov_dpp(__float_as_int(v), CTRL, 0xF, 0xF, true);
    return fminf(v, __int_as_float(o));
}
__device__ __forceinline__ float swz16min_f32(float v) {
    const int o = __builtin_amdgcn_ds_swizzle(__float_as_int(v), 0x401F); // xor16
    return fminf(v, __int_as_float(o));
}
__device__ __forceinline__ float half32min_f32(float v, int lane) {
#if __has_builtin(__builtin_amdgcn_permlane32_swap)
    v2i r = __builtin_amdgcn_permlane32_swap(__float_as_int(v), __float_as_int(v), false, false);
    const int o = (lane < 32) ? r[1] : r[0];
#else
    const int o = __shfl_xor(__float_as_int(v), 32, 64);
#endif
    return fminf(v, __int_as_float(o));
}
__device__ __forceinline__ float wavemin_f32(float v, int lane) {
    v = dppmin_f32<0xB1>(v);    // quad_perm xor1
    v = dppmin_f32<0x4E>(v);    // quad_perm xor2
    v = dppmin_f32<0x124>(v);   // row_ror:4
    v = dppmin_f32<0x128>(v);   // row_ror:8
    v = swz16min_f32(v);        // xor16
    v = half32min_f32(v, lane); // cross-32
    return v;
}

// ------ Kernel A: dense-load + LDS transpose, per-quarter top-16 keys ------
// LDS tile: 1024 points (3072 floats) stored padded: float group k (12 floats
// = 4 points) lives at float offset 13k (+1 pad) -> both b128 writes and b64
// (x,y) reads spread over all 32 banks.
__global__ __launch_bounds__(BDIM, 8) void select_kernel(
    const float* __restrict__ lg,      // (2,)
    const float* __restrict__ coords,  // (B, N, 3)
    ull* __restrict__ keys)            // (B, 4, 16) u64 workspace
{
    __shared__ float tile[3332];       // 13*256 + 4 floats, ~13.3 KB
    __shared__ float twave[4];
    __shared__ ull   cand[CAP];
    __shared__ int   ccnt;

    const int blk  = blockIdx.x;
    const int row  = blk >> 2;
    const int q    = blk & 3;
    const int tid  = threadIdx.x;
    const int lane = tid & 63;
    const int wid  = tid >> 6;
    const float lg0 = lg[0];
    const float lg1 = lg[1];

    if (tid == 0) ccnt = 0;

    // chunk base of this quarter: (row*8192 + q*2048)*3 floats / 4
    const float4* c4 = reinterpret_cast<const float4*>(coords)
                       + (size_t)row * (NPTS * 3 / 4) + q * (QPTS * 3 / 4);

    float dd[8];
    #pragma unroll
    for (int it = 0; it < 2; ++it) {
        // ---- dense global loads: lane i reads chunk base+i (1KB/instr/wave)
        const int cbase = it * 768;
        const float4 va = c4[cbase + tid];
        const float4 vb = c4[cbase + 256 + tid];
        const float4 vc = c4[cbase + 512 + tid];
        __syncthreads();   // tile free (prev iter's reads done)
        {   // chunk c holds floats 4c..4c+3; write at 13*(c/3)+4*(c%3)
            const int c0 = tid,      k0 = c0 / 3, r0 = c0 % 3;
            const int c1 = 256 + tid, k1 = c1 / 3, r1 = c1 % 3;
            const int c2 = 512 + tid, k2 = c2 / 3, r2 = c2 % 3;
            *reinterpret_cast<float4*>(&tile[13 * k0 + 4 * r0]) = va;
            *reinterpret_cast<float4*>(&tile[13 * k1 + 4 * r1]) = vb;
            *reinterpret_cast<float4*>(&tile[13 * k2 + 4 * r2]) = vc;
        }
        __syncthreads();
        // ---- read (x,y) of points 4*tid..4*tid+3: float offset 13*tid+3j
        #pragma unroll
        for (int j = 0; j < 4; ++j) {
            const float2 xy = *reinterpret_cast<const float2*>(&tile[13 * tid + 3 * j]);
            // match numpy rounding: sub, sub, mul, mul, add — no fma contraction
            const float t0 = __fsub_rn(lg0, xy.x);
            const float t1 = __fsub_rn(lg1, xy.y);
            dd[it * 4 + j] = __fadd_rn(__fmul_rn(t0, t0), __fmul_rn(t1, t1));
        }
    }
    // point index of slot (it,j): (it<<10) + (tid<<2) + j  (same as before)

    // ---- thread min ----
    const float m = fminf(fminf(fminf(dd[0], dd[1]), fminf(dd[2], dd[3])),
                          fminf(fminf(dd[4], dd[5]), fminf(dd[6], dd[7])));

    // ---- per-wave 4th-smallest thread-min; T = max over waves ----
    // (each wave then has >=4 thread-mins <= T -> >=16 points <= T block-wide)
    float tw;
    {
        float loc = m;
        #pragma unroll
        for (int r = 0; r < 4; ++r) {
            const float wmin = wavemin_f32(loc, lane);
            if (r == 3) { tw = wmin; break; }
            if (loc == wmin) loc = FLT_MAX;
        }
    }
    if (lane == 0) twave[wid] = tw;
    __syncthreads();
    const float T = fmaxf(fmaxf(twave[0], twave[1]), fmaxf(twave[2], twave[3]));

    // ---- candidates with d <= T (contains all quarter-top-16) ----
    #pragma unroll
    for (int it = 0; it < 2; ++it) {
        #pragma unroll
        for (int j = 0; j < 4; ++j) {
            const float d = dd[it * 4 + j];
            if (d <= T) {
                const int pos = atomicAdd(&ccnt, 1);
                if (pos < CAP)
                    cand[pos] = mkkey(d, (q << 11) + (it << 10) + (tid << 2) + j);
            }
        }
    }
    __syncthreads();

    // ---- exact quarter-top-16 by rank (unique keys -> rank is exact) ----
    if (wid == 0) {
        int cc = ccnt; if (cc > CAP) cc = CAP;
        for (int s = lane; s < cc; s += 64) {
            const ull k = cand[s];
            int rank = 0;
            for (int j = 0; j < cc; ++j) rank += (cand[j] < k);
            if (rank < KSEL) keys[(size_t)row * 64 + q * 16 + rank] = k;
        }
    }
}

// ------ Kernel B: merge 4x16 keys, gather, feature, MLP (1 row/block) ------
__global__ __launch_bounds__(BDIM) void mlp_kernel(
    const float* __restrict__ lg,
    const float* __restrict__ coords,
    const float* __restrict__ params,
    const ull* __restrict__ keys,
    const float* __restrict__ W1, const float* __restrict__ b1,
    const float* __restrict__ W2, const float* __restrict__ b2,
    const float* __restrict__ W3, const float* __restrict__ b3,
    float* __restrict__ out)
{
    __shared__ ull   wkeys[64];
    __shared__ int   selb[KSEL];
    __shared__ float pbuf[KSEL][PD_];
    __shared__ float cbuf[KSEL][2];
    __shared__ float xvec[DIN];
    __shared__ float h1s[HID];
    __shared__ float h2s[HID];

    const int tid = threadIdx.x;
    const int row = blockIdx.x;

    // ---- merge: exact top-16 of the row's 64 quarter keys (rank trick) ----
    if (tid < 64) wkeys[tid] = keys[(size_t)row * 64 + tid];
    __syncthreads();
    if (tid < 64) {
        const ull myk = wkeys[tid];
        int rank = 0;
        #pragma unroll 8
        for (int j = 0; j < 64; ++j) rank += (wkeys[j] < myk);
        if (rank < KSEL) selb[rank] = (int)(unsigned)myk;   // argsort order
    }
    __syncthreads();

    {   // params gather: 256 threads = 16 neighbors x 16 dims (coalesced rows)
        const int k = tid >> 4, p = tid & 15;
        pbuf[k][p] = params[((size_t)row * NPTS + selb[k]) * PD_ + p];
    }
    if (tid < 2 * KSEL) {
        const int k = tid >> 1, c = tid & 1;
        cbuf[k][c] = coords[((size_t)row * NPTS + selb[k]) * 3 + c];
    }
    __syncthreads();

    if (tid < DIN) {
        float v;
        if (tid < 2) {
            v = lg[tid];
        } else if (tid < 4) {
            float s = 0.f;
            for (int k = 0; k < KSEL; ++k) s += cbuf[k][tid - 2];
            v = s * (1.f / 16.f);
        } else {
            float s = 0.f;
            for (int k = 0; k < KSEL; ++k) s += pbuf[k][tid - 4];
            v = s * (1.f / 16.f);
        }
        xvec[tid] = v;
    }
    __syncthreads();

    if (tid < HID) {
        float acc = b1[tid];
        #pragma unroll
        for (int i = 0; i < DIN; ++i) acc = fmaf(xvec[i], W1[i * HID + tid], acc);
        h1s[tid] = fmaxf(acc, 0.f);
    }
    __syncthreads();
    if (tid < HID) {
        float acc = b2[tid];
        #pragma unroll 16
        for (int i = 0; i < HID; ++i) acc = fmaf(h1s[i], W2[i * HID + tid], acc);
        h2s[tid] = fmaxf(acc, 0.f);
    }
    __syncthreads();
    {
        float acc = b3[tid];
        #pragma unroll 16
        for (int i = 0; i < HID; ++i) acc = fmaf(h2s[i], W3[i * DOUT + tid], acc);
        out[(size_t)row * DOUT + tid] = acc;
    }
}

extern "C" void kernel_launch(void* const* d_in, const int* in_sizes, int n_in,
                              void* d_out, int out_size, void* d_ws, size_t ws_size,
                              hipStream_t stream) {
    const float* lg     = (const float*)d_in[0];
    const float* coords = (const float*)d_in[1];
    const float* params = (const float*)d_in[2];
    const float* W1     = (const float*)d_in[3];
    const float* b1     = (const float*)d_in[4];
    const float* W2     = (const float*)d_in[5];
    const float* b2     = (const float*)d_in[6];
    const float* W3     = (const float*)d_in[7];
    const float* b3     = (const float*)d_in[8];
    float* out          = (float*)d_out;
    ull*   keys         = (ull*)d_ws;            // (B, 4, 16) u64 = 512 KB

    const int Brows = in_sizes[1] / (NPTS * 3);  // 1024
    select_kernel<<<dim3(Brows * 4), dim3(BDIM), 0, stream>>>(lg, coords, keys);
    mlp_kernel<<<dim3(Brows), dim3(BDIM), 0, stream>>>(
        lg, coords, params, keys, W1, b1, W2, b2, W3, b3, out);
}

// Round 9
// 29.167 us; speedup vs baseline: 19.0009x; 1.1543x over previous
//
#include <hip/hip_runtime.h>
#include <cfloat>

typedef unsigned long long ull;
typedef int v2i __attribute__((ext_vector_type(2)));

constexpr int BDIM = 256;
constexpr int NPTS = 8192;
constexpr int KSEL = 16;
constexpr int PD_  = 16;
constexpr int DIN  = 20;
constexpr int HID  = 128;
constexpr int DOUT = 256;
constexpr int CAP  = 384;      // candidate capacity (E[cnt] ~ 40-80)

__device__ __forceinline__ ull mkkey(float d, int n) {
    // positive-float bits are order-monotone; low 32 bits = index (tie-break)
    return ((ull)__float_as_uint(d) << 32) | (unsigned int)n;
}

// ---------- f32 wave butterfly min (DPP + 1 ds_swizzle + permlane32) --------
template<int CTRL>
__device__ __forceinline__ float dppmin_f32(float v) {
    const int o = __builtin_amdgcn_mov_dpp(__float_as_int(v), CTRL, 0xF, 0xF, true);
    return fminf(v, __int_as_float(o));
}
__device__ __forceinline__ float swz16min_f32(float v) {
    const int o = __builtin_amdgcn_ds_swizzle(__float_as_int(v), 0x401F); // xor16
    return fminf(v, __int_as_float(o));
}
__device__ __forceinline__ float half32min_f32(float v, int lane) {
#if __has_builtin(__builtin_amdgcn_permlane32_swap)
    v2i r = __builtin_amdgcn_permlane32_swap(__float_as_int(v), __float_as_int(v), false, false);
    const int o = (lane < 32) ? r[1] : r[0];
#else
    const int o = __shfl_xor(__float_as_int(v), 32, 64);
#endif
    return fminf(v, __int_as_float(o));
}
__device__ __forceinline__ float wavemin_f32(float v, int lane) {
    v = dppmin_f32<0xB1>(v);    // quad_perm xor1
    v = dppmin_f32<0x4E>(v);    // quad_perm xor2
    v = dppmin_f32<0x124>(v);   // row_ror:4
    v = dppmin_f32<0x128>(v);   // row_ror:8
    v = swz16min_f32(v);        // xor16
    v = half32min_f32(v, lane); // cross-32
    return v;
}

// ---- ONE kernel: stream + threshold top-16 + gather + feature + MLP -------
__global__ __launch_bounds__(BDIM, 4) void encoder_kernel(
    const float* __restrict__ lg,      // (2,)
    const float* __restrict__ coords,  // (B, N, 3)
    const float* __restrict__ params,  // (B, N, 16)
    const float* __restrict__ W1, const float* __restrict__ b1,
    const float* __restrict__ W2, const float* __restrict__ b2,
    const float* __restrict__ W3, const float* __restrict__ b3,
    float* __restrict__ out)           // (B, 256)
{
    __shared__ float twave[4];
    __shared__ ull   cand[CAP];
    __shared__ int   ccnt;
    __shared__ int   selb[KSEL];
    __shared__ float pbuf[KSEL][PD_ + 1];
    __shared__ float cbuf[KSEL][2];
    __shared__ float xvec[DIN];
    __shared__ float h1s[HID];
    __shared__ float h2s[HID];

    const int row  = blockIdx.x;
    const int tid  = threadIdx.x;
    const int lane = tid & 63;
    const int wid  = tid >> 6;
    const float lg0 = lg[0];
    const float lg1 = lg[1];

    if (tid == 0) ccnt = 0;

    // ---- Phase 1: distances for 32 points/thread, f32 registers ----
    const float4* c4 = reinterpret_cast<const float4*>(coords + (size_t)row * NPTS * 3);

    float dd[32];
    #pragma unroll
    for (int it = 0; it < 8; ++it) {
        const int g = it * BDIM + tid;
        const float4 qa = c4[3 * g + 0];
        const float4 qb = c4[3 * g + 1];
        const float4 qc = c4[3 * g + 2];
        const float px[4] = {qa.x, qa.w, qb.z, qc.y};
        const float py[4] = {qa.y, qb.x, qb.w, qc.z};
        #pragma unroll
        for (int j = 0; j < 4; ++j) {
            // match numpy rounding: sub, sub, mul, mul, add — no fma contraction
            const float t0 = __fsub_rn(lg0, px[j]);
            const float t1 = __fsub_rn(lg1, py[j]);
            dd[it * 4 + j] = __fadd_rn(__fmul_rn(t0, t0), __fmul_rn(t1, t1));
        }
    }
    // global point index of slot (it,j): (it<<10) + (tid<<2) + j

    // ---- Phase 2a: per-thread min (register tree) ----
    float m;
    {
        float t[16];
        #pragma unroll
        for (int l = 0; l < 16; ++l) t[l] = fminf(dd[2 * l], dd[2 * l + 1]);
        #pragma unroll
        for (int s = 8; s > 0; s >>= 1)
            #pragma unroll
            for (int l = 0; l < 16; ++l) if (l < s) t[l] = fminf(t[l], t[l + s]);
        m = t[0];
    }

    // ---- Phase 2b: per-wave 4th-smallest thread-min; T = max over waves ----
    // (each wave then has >=4 thread-mins <= T -> >=16 points <= T block-wide;
    //  tie-collapse only raises T = safe superset)
    float tw;
    {
        float loc = m;
        #pragma unroll
        for (int r = 0; r < 4; ++r) {
            const float wmin = wavemin_f32(loc, lane);
            if (r == 3) { tw = wmin; break; }
            if (loc == wmin) loc = FLT_MAX;
        }
    }
    if (lane == 0) twave[wid] = tw;
    __syncthreads();
    const float T = fmaxf(fmaxf(twave[0], twave[1]), fmaxf(twave[2], twave[3]));

    // ---- Phase 2c: candidates with d <= T (contains all top-16) ----
    #pragma unroll
    for (int it = 0; it < 8; ++it) {
        #pragma unroll
        for (int j = 0; j < 4; ++j) {
            const float d = dd[it * 4 + j];
            if (d <= T) {
                const int pos = atomicAdd(&ccnt, 1);
                if (pos < CAP)
                    cand[pos] = mkkey(d, (it << 10) + (tid << 2) + j);
            }
        }
    }
    __syncthreads();

    // ---- Phase 2d: exact top-16 by rank (unique keys -> rank exact) ----
    if (wid == 0) {
        int cc = ccnt; if (cc > CAP) cc = CAP;
        for (int s = lane; s < cc; s += 64) {
            const ull k = cand[s];
            int rank = 0;
            for (int j = 0; j < cc; ++j) rank += (cand[j] < k);
            if (rank < KSEL) selb[rank] = (int)(unsigned)k;   // argsort order
        }
    }
    __syncthreads();

    // ---- Phase 3: coalesced gather of the 16 neighbor rows ----
    {   // params: 256 threads = 16 neighbors x 16 dims (one line per row)
        const int k = tid >> 4, p = tid & 15;
        pbuf[k][p] = params[((size_t)row * NPTS + selb[k]) * PD_ + p];
    }
    if (tid < 2 * KSEL) {
        const int k = tid >> 1, c = tid & 1;
        cbuf[k][c] = coords[((size_t)row * NPTS + selb[k]) * 3 + c];
    }
    __syncthreads();

    if (tid < DIN) {
        float v;
        if (tid < 2) {
            v = lg[tid];
        } else if (tid < 4) {
            float s = 0.f;
            for (int k = 0; k < KSEL; ++k) s += cbuf[k][tid - 2];
            v = s * (1.f / 16.f);
        } else {
            float s = 0.f;
            for (int k = 0; k < KSEL; ++k) s += pbuf[k][tid - 4];
            v = s * (1.f / 16.f);
        }
        xvec[tid] = v;
    }
    __syncthreads();

    // ---- Phase 4: MLP 20 -> 128 -> 128 -> 256 (weights L1/L2-resident) ----
    if (tid < HID) {
        float acc = b1[tid];
        #pragma unroll
        for (int i = 0; i < DIN; ++i) acc = fmaf(xvec[i], W1[i * HID + tid], acc);
        h1s[tid] = fmaxf(acc, 0.f);
    }
    __syncthreads();
    if (tid < HID) {
        float acc = b2[tid];
        #pragma unroll 16
        for (int i = 0; i < HID; ++i) acc = fmaf(h1s[i], W2[i * HID + tid], acc);
        h2s[tid] = fmaxf(acc, 0.f);
    }
    __syncthreads();
    {
        float acc = b3[tid];
        #pragma unroll 16
        for (int i = 0; i < HID; ++i) acc = fmaf(h2s[i], W3[i * DOUT + tid], acc);
        out[(size_t)row * DOUT + tid] = acc;
    }
}

extern "C" void kernel_launch(void* const* d_in, const int* in_sizes, int n_in,
                              void* d_out, int out_size, void* d_ws, size_t ws_size,
                              hipStream_t stream) {
    const float* lg     = (const float*)d_in[0];
    const float* coords = (const float*)d_in[1];
    const float* params = (const float*)d_in[2];
    const float* W1     = (const float*)d_in[3];
    const float* b1     = (const float*)d_in[4];
    const float* W2     = (const float*)d_in[5];
    const float* b2     = (const float*)d_in[6];
    const float* W3     = (const float*)d_in[7];
    const float* b3     = (const float*)d_in[8];
    float* out          = (float*)d_out;

    const int Brows = in_sizes[1] / (NPTS * 3);  // 1024
    encoder_kernel<<<dim3(Brows), dim3(BDIM), 0, stream>>>(
        lg, coords, params, W1, b1, W2, b2, W3, b3, out);
}